// Round 1
// baseline (668.315 us; speedup 1.0000x reference)
//
#include <hip/hip_runtime.h>
#include <hip/hip_bf16.h>
#include <hip/hip_cooperative_groups.h>

namespace cg = cooperative_groups;

#define HIDDEN 128
#define K1 512          // 4*HIDDEN
#define C2 256          // 2*HIDDEN

// ---------------------------------------------------------------------------
// Fused single-launch pipeline (cooperative):
//   Phase 0: fold the two linear layers:
//       Weff[c][j] = sum_k W1[c][k]*W2[k][j]   (interleaved weff[c*2+j])
//       beff[j]    = b1 @ W2[:,j] + b2[j]
//   grid.sync()
//   Phase 1: per-node projection table
//       tab[v] = (P0+beff0, P1+beff1, Q0, Q1), P=feat[v].Weff_top, Q=.Weff_bot
//   grid.sync()
//   Phase 2: per-edge combine: logit_j = P_j[src] + Q_j[dst]; 2-way softmax.
// All phases grid-stride, so any co-resident grid size is correct.
// ---------------------------------------------------------------------------
__global__ __launch_bounds__(256, 4) void fused_kernel(
    const float* __restrict__ feat, const int* __restrict__ edges,
    const float* __restrict__ W1, const float* __restrict__ b1,
    const float* __restrict__ W2, const float* __restrict__ b2,
    float* __restrict__ weff, float* __restrict__ beff,
    float4* __restrict__ tab, float2* __restrict__ out,
    int n_nodes, int n_edges)
{
    cg::grid_group grid = cg::this_grid();
    const int lane   = threadIdx.x & 63;
    const int wave   = (blockIdx.x * blockDim.x + threadIdx.x) >> 6;
    const int nwaves = (gridDim.x * blockDim.x) >> 6;

    // ---------------- Phase 0: fold ----------------
    for (int w = wave; w < 514; w += nwaves) {
        if (w < 512) {
            const int i = w >> 1, j = w & 1;
            const float* r = W1 + i * K1 + lane * 8;
            const float4 p = *(const float4*)r;
            const float4 q = *(const float4*)(r + 4);
            const float* c = W2 + lane * 16 + j;
            float acc = p.x * c[0]  + p.y * c[2]  + p.z * c[4]  + p.w * c[6]
                      + q.x * c[8]  + q.y * c[10] + q.z * c[12] + q.w * c[14];
            #pragma unroll
            for (int off = 32; off; off >>= 1) acc += __shfl_xor(acc, off, 64);
            if (lane == 0) weff[i * 2 + j] = acc;
        } else {
            const int j = w - 512;
            const float* bb = b1 + lane * 8;
            const float* c = W2 + lane * 16 + j;
            float acc = bb[0] * c[0]  + bb[1] * c[2]  + bb[2] * c[4]  + bb[3] * c[6]
                      + bb[4] * c[8]  + bb[5] * c[10] + bb[6] * c[12] + bb[7] * c[14];
            #pragma unroll
            for (int off = 32; off; off >>= 1) acc += __shfl_xor(acc, off, 64);
            if (lane == 0) beff[j] = acc + b2[j];
        }
    }
    __threadfence();          // agent-scope release (cross-XCD L2 writeback)
    grid.sync();
    __threadfence();          // agent-scope acquire (invalidate stale L2)

    // ---------------- Phase 1: node projection ----------------
    {
        const int t = lane & 31;                 // float4 slot within the row
        const int half = lane >> 5;
        // weights hoisted out of the node loop (L1/L2-resident, 64 B/lane)
        const float4 a0 = *(const float4*)(weff + t * 8);
        const float4 a1 = *(const float4*)(weff + t * 8 + 4);
        const float4 c0 = *(const float4*)(weff + 256 + t * 8);
        const float4 c1 = *(const float4*)(weff + 256 + t * 8 + 4);
        const float be0 = beff[0], be1 = beff[1];
        const int npairs = (n_nodes + 1) >> 1;
        for (int pair = wave; pair < npairs; pair += nwaves) {
            const int v  = pair * 2 + half;
            const int vc = v < n_nodes ? v : n_nodes - 1;
            const float4 f = ((const float4*)(feat + (long)vc * HIDDEN))[t];
            float p0 = f.x*a0.x + f.y*a0.z + f.z*a1.x + f.w*a1.z;
            float p1 = f.x*a0.y + f.y*a0.w + f.z*a1.y + f.w*a1.w;
            float q0 = f.x*c0.x + f.y*c0.z + f.z*c1.x + f.w*c1.z;
            float q1 = f.x*c0.y + f.y*c0.w + f.z*c1.y + f.w*c1.w;
            #pragma unroll
            for (int off = 16; off; off >>= 1) {   // stays within 32-lane half
                p0 += __shfl_xor(p0, off, 64);
                p1 += __shfl_xor(p1, off, 64);
                q0 += __shfl_xor(q0, off, 64);
                q1 += __shfl_xor(q1, off, 64);
            }
            if (t == 0 && v < n_nodes)
                tab[v] = make_float4(p0 + be0, p1 + be1, q0, q1);
        }
    }
    __threadfence();
    grid.sync();
    __threadfence();

    // ---------------- Phase 2: edges ----------------
    {
        const int gtid = blockIdx.x * blockDim.x + threadIdx.x;
        const int gsz  = gridDim.x * blockDim.x;
        const float* tabf = (const float*)tab;
        for (int e = gtid; e < n_edges; e += gsz) {
            const int s = edges[e];
            const int d = edges[n_edges + e];
            const float2 ps = *(const float2*)(tabf + (long)s * 4);     // P0+b0, P1+b1
            const float2 qd = *(const float2*)(tabf + (long)d * 4 + 2); // Q0, Q1
            const float l0 = ps.x + qd.x, l1 = ps.y + qd.y;
            const float m = fmaxf(l0, l1);
            const float x0 = __expf(l0 - m), x1 = __expf(l1 - m);
            const float inv = 1.0f / (x0 + x1);
            out[e] = make_float2(x0 * inv, x1 * inv);
        }
    }
}

// ---------------------------------------------------------------------------
// Proven 3-kernel path (R1-R?) kept as fallback if cooperative launch is
// unavailable.
// ---------------------------------------------------------------------------
__global__ __launch_bounds__(256) void fold_kernel(
    const float* __restrict__ W1, const float* __restrict__ b1,
    const float* __restrict__ W2, const float* __restrict__ b2,
    float* __restrict__ weff, float* __restrict__ beff) {
    const int lane = threadIdx.x & 63;
    const int w = (blockIdx.x * blockDim.x + threadIdx.x) >> 6;
    if (w < 512) {
        const int i = w >> 1, j = w & 1;
        const float* r = W1 + i * K1 + lane * 8;
        const float4 p = *(const float4*)r;
        const float4 q = *(const float4*)(r + 4);
        const float* c = W2 + lane * 16 + j;
        float acc = p.x * c[0]  + p.y * c[2]  + p.z * c[4]  + p.w * c[6]
                  + q.x * c[8]  + q.y * c[10] + q.z * c[12] + q.w * c[14];
        #pragma unroll
        for (int off = 32; off; off >>= 1) acc += __shfl_xor(acc, off, 64);
        if (lane == 0) weff[i * 2 + j] = acc;
    } else if (w < 514) {
        const int j = w - 512;
        const float* bb = b1 + lane * 8;
        const float* c = W2 + lane * 16 + j;
        float acc = bb[0] * c[0]  + bb[1] * c[2]  + bb[2] * c[4]  + bb[3] * c[6]
                  + bb[4] * c[8]  + bb[5] * c[10] + bb[6] * c[12] + bb[7] * c[14];
        #pragma unroll
        for (int off = 32; off; off >>= 1) acc += __shfl_xor(acc, off, 64);
        if (lane == 0) beff[j] = acc + b2[j];
    }
}

__global__ __launch_bounds__(256) void nodeproj_kernel(
    const float* __restrict__ feat, const float* __restrict__ weff,
    const float* __restrict__ beff, float4* __restrict__ tab, int n_nodes) {
    const int lane = threadIdx.x & 63;
    const int wave = (blockIdx.x * blockDim.x + threadIdx.x) >> 6;
    const int v = wave * 2 + (lane >> 5);
    if (wave * 2 >= n_nodes) return;           // wave-uniform exit
    const int vc = v < n_nodes ? v : n_nodes - 1;
    const int t = lane & 31;

    const float4 f = ((const float4*)(feat + (long)vc * HIDDEN))[t];
    const float4 a0 = *(const float4*)(weff + t * 8);
    const float4 a1 = *(const float4*)(weff + t * 8 + 4);
    const float4 c0 = *(const float4*)(weff + 256 + t * 8);
    const float4 c1 = *(const float4*)(weff + 256 + t * 8 + 4);

    float p0 = f.x*a0.x + f.y*a0.z + f.z*a1.x + f.w*a1.z;
    float p1 = f.x*a0.y + f.y*a0.w + f.z*a1.y + f.w*a1.w;
    float q0 = f.x*c0.x + f.y*c0.z + f.z*c1.x + f.w*c1.z;
    float q1 = f.x*c0.y + f.y*c0.w + f.z*c1.y + f.w*c1.w;

    #pragma unroll
    for (int off = 16; off; off >>= 1) {
        p0 += __shfl_xor(p0, off, 64);
        p1 += __shfl_xor(p1, off, 64);
        q0 += __shfl_xor(q0, off, 64);
        q1 += __shfl_xor(q1, off, 64);
    }

    if (t == 0 && v < n_nodes)
        tab[v] = make_float4(p0 + beff[0], p1 + beff[1], q0, q1);
}

__global__ __launch_bounds__(256) void edge_lite_kernel(
    const int* __restrict__ edges, const float* __restrict__ tab,
    float2* __restrict__ out, int n_edges) {
    const int e = blockIdx.x * blockDim.x + threadIdx.x;
    if (e >= n_edges) return;
    const int s = edges[e];
    const int d = edges[n_edges + e];
    const float2 ps = *(const float2*)(tab + (long)s * 4);
    const float2 qd = *(const float2*)(tab + (long)d * 4 + 2);
    const float l0 = ps.x + qd.x, l1 = ps.y + qd.y;
    const float m = fmaxf(l0, l1);
    const float x0 = __expf(l0 - m), x1 = __expf(l1 - m);
    const float inv = 1.0f / (x0 + x1);
    out[e] = make_float2(x0 * inv, x1 * inv);
}

// Fallback (fp32 direct edge kernel) — only if ws_size is tiny.
__global__ __launch_bounds__(256) void edge_kernel(
    const float* __restrict__ feat, const int* __restrict__ edges,
    const float* __restrict__ weff, const float* __restrict__ beff,
    float* __restrict__ out, int n_edges) {
    const int lane = threadIdx.x & 63;
    const int wave = (blockIdx.x * blockDim.x + threadIdx.x) >> 6;
    const int n_waves = (gridDim.x * blockDim.x) >> 6;
    const int g = lane >> 4, sub = lane & 15;
    const int half = sub >> 3, p = sub & 7;

    const float* wb = weff + (half * 128 + p * 16) * 2;
    const float4 w0 = *(const float4*)(wb +  0);
    const float4 w1 = *(const float4*)(wb +  4);
    const float4 w2 = *(const float4*)(wb +  8);
    const float4 w3 = *(const float4*)(wb + 12);
    const float4 w4 = *(const float4*)(wb + 16);
    const float4 w5 = *(const float4*)(wb + 20);
    const float4 w6 = *(const float4*)(wb + 24);
    const float4 w7 = *(const float4*)(wb + 28);
    const float b0 = beff[0], b1v = beff[1];
    const int* idxbase = edges + half * n_edges;

    for (int e0 = wave * 4; e0 < n_edges; e0 += n_waves * 4) {
        const int e  = e0 + g;
        const int ec = e < n_edges ? e : n_edges - 1;
        const int row = idxbase[ec];
        const float* fr = feat + (long)row * HIDDEN + p * 16;
        const float4 f0 = *(const float4*)(fr +  0);
        const float4 f1 = *(const float4*)(fr +  4);
        const float4 f2 = *(const float4*)(fr +  8);
        const float4 f3 = *(const float4*)(fr + 12);
        float a0 = f0.x*w0.x + f0.y*w0.z + f0.z*w1.x + f0.w*w1.z;
        float a1 = f0.x*w0.y + f0.y*w0.w + f0.z*w1.y + f0.w*w1.w;
        a0 += f1.x*w2.x + f1.y*w2.z + f1.z*w3.x + f1.w*w3.z;
        a1 += f1.x*w2.y + f1.y*w2.w + f1.z*w3.y + f1.w*w3.w;
        a0 += f2.x*w4.x + f2.y*w4.z + f2.z*w5.x + f2.w*w5.z;
        a1 += f2.x*w4.y + f2.y*w4.w + f2.z*w5.y + f2.w*w5.w;
        a0 += f3.x*w6.x + f3.y*w6.z + f3.z*w7.x + f3.w*w7.z;
        a1 += f3.x*w6.y + f3.y*w6.w + f3.z*w7.y + f3.w*w7.w;
        #pragma unroll
        for (int off = 8; off; off >>= 1) {
            a0 += __shfl_xor(a0, off, 64);
            a1 += __shfl_xor(a1, off, 64);
        }
        if (sub == 0 && e < n_edges) {
            const float l0 = a0 + b0, l1 = a1 + b1v;
            const float m = fmaxf(l0, l1);
            const float x0 = __expf(l0 - m), x1 = __expf(l1 - m);
            const float inv = 1.0f / (x0 + x1);
            *(float2*)(out + (long)e * 2) = make_float2(x0 * inv, x1 * inv);
        }
    }
}

extern "C" void kernel_launch(void* const* d_in, const int* in_sizes, int n_in,
                              void* d_out, int out_size, void* d_ws, size_t ws_size,
                              hipStream_t stream) {
    const float* feat = (const float*)d_in[0];   // 100000 x 128
    const int*   edges = (const int*)d_in[1];    // 2 x 500000
    const float* W1 = (const float*)d_in[2];     // 256 x 512
    const float* b1 = (const float*)d_in[3];     // 512
    const float* W2 = (const float*)d_in[4];     // 512 x 2
    const float* b2 = (const float*)d_in[5];     // 2
    float* out = (float*)d_out;                  // 500000 x 2

    const int n_nodes = in_sizes[0] / HIDDEN;    // 100000
    const int n_edges = in_sizes[1] / 2;         // 500000

    float* weff = (float*)d_ws;                  // 512 floats @ 0
    float* beff = weff + 512;                    // 2 floats
    float4* tab = (float4*)((char*)d_ws + 4096); // n_nodes x float4
    const size_t need = 4096 + (size_t)n_nodes * sizeof(float4);

    // One-time setup: cooperative-launch support + validated co-resident grid.
    // Host-only queries — no allocation, no stream ops (graph-capture safe).
    static int s_coop = -1;
    static int s_blocks = 0;
    if (s_coop < 0) {
        int dev = 0;
        hipGetDevice(&dev);
        int coop = 0;
        hipDeviceGetAttribute(&coop, hipDeviceAttributeCooperativeLaunch, dev);
        int cus = 0;
        hipDeviceGetAttribute(&cus, hipDeviceAttributeMultiprocessorCount, dev);
        if (cus <= 0) cus = 256;
        int occ = 0;
        hipOccupancyMaxActiveBlocksPerMultiprocessor(&occ, fused_kernel, 256, 0);
        if (occ < 1) coop = 0;                   // can't guarantee residency
        long b = (long)occ * cus;
        if (b > 2048) b = 2048;                  // cap: sync cost vs parallelism
        if (b < 1) b = 1;
        s_blocks = (int)b;
        s_coop = coop;
    }

    if (ws_size >= need && s_coop > 0) {
        // Single fused cooperative launch: fold -> sync -> nodeproj -> sync -> edges
        int nn = n_nodes, ne = n_edges;
        void* args[] = {
            (void*)&feat, (void*)&edges, (void*)&W1, (void*)&b1,
            (void*)&W2, (void*)&b2, (void*)&weff, (void*)&beff,
            (void*)&tab, (void*)&out, (void*)&nn, (void*)&ne
        };
        hipLaunchCooperativeKernel((const void*)fused_kernel,
                                   dim3(s_blocks), dim3(256), args, 0, stream);
    } else if (ws_size >= need) {
        // Proven 3-kernel path.
        fold_kernel<<<129, 256, 0, stream>>>(W1, b1, W2, b2, weff, beff);
        const int np_blocks = (n_nodes + 7) / 8;
        nodeproj_kernel<<<np_blocks, 256, 0, stream>>>(feat, weff, beff, tab, n_nodes);
        const int e_blocks = (n_edges + 255) / 256;
        edge_lite_kernel<<<e_blocks, 256, 0, stream>>>(edges, (const float*)tab,
                                                       (float2*)out, n_edges);
    } else {
        fold_kernel<<<129, 256, 0, stream>>>(W1, b1, W2, b2, weff, beff);
        edge_kernel<<<2048, 256, 0, stream>>>(feat, edges, weff, beff, out, n_edges);
    }
}

// Round 2
// 105.217 us; speedup vs baseline: 6.3517x; 6.3517x over previous
//
#include <hip/hip_runtime.h>
#include <hip/hip_bf16.h>

#define HIDDEN 128
#define K1 512          // 4*HIDDEN
#define C2 256          // 2*HIDDEN

// ---------------------------------------------------------------------------
// Kernel 1: fold the two linear layers (proven since R1).
//   Weff[c][j] = sum_k W1[c][k]*W2[k][j]   (interleaved weff[c*2+j])
//   beff[j]    = b1 @ W2[:,j] + b2[j]
// ---------------------------------------------------------------------------
__global__ __launch_bounds__(256) void fold_kernel(
    const float* __restrict__ W1, const float* __restrict__ b1,
    const float* __restrict__ W2, const float* __restrict__ b2,
    float* __restrict__ weff, float* __restrict__ beff) {
    const int lane = threadIdx.x & 63;
    const int w = (blockIdx.x * blockDim.x + threadIdx.x) >> 6;
    if (w < 512) {
        const int i = w >> 1, j = w & 1;
        const float* r = W1 + i * K1 + lane * 8;
        const float4 p = *(const float4*)r;
        const float4 q = *(const float4*)(r + 4);
        const float* c = W2 + lane * 16 + j;
        float acc = p.x * c[0]  + p.y * c[2]  + p.z * c[4]  + p.w * c[6]
                  + q.x * c[8]  + q.y * c[10] + q.z * c[12] + q.w * c[14];
        #pragma unroll
        for (int off = 32; off; off >>= 1) acc += __shfl_xor(acc, off, 64);
        if (lane == 0) weff[i * 2 + j] = acc;
    } else if (w < 514) {
        const int j = w - 512;
        const float* bb = b1 + lane * 8;
        const float* c = W2 + lane * 16 + j;
        float acc = bb[0] * c[0]  + bb[1] * c[2]  + bb[2] * c[4]  + bb[3] * c[6]
                  + bb[4] * c[8]  + bb[5] * c[10] + bb[6] * c[12] + bb[7] * c[14];
        #pragma unroll
        for (int off = 32; off; off >>= 1) acc += __shfl_xor(acc, off, 64);
        if (lane == 0) beff[j] = acc + b2[j];
    }
}

// ---------------------------------------------------------------------------
// Kernel 2: per-node projection. For each node v:
//   P_j[v] = feat[v] . Weff[0:128, j]   (src half)
//   Q_j[v] = feat[v] . Weff[128:256, j] (dst half)
// tab[v] = (P0 + beff0, P1 + beff1, Q0, Q1).
// 2 nodes per wave: lanes [0,32) node 2w, [32,64) node 2w+1; lane t covers
// floats [t*4, t*4+4) of the row (one float4 -> wave reads 1 KiB contiguous).
// ---------------------------------------------------------------------------
__global__ __launch_bounds__(256) void nodeproj_kernel(
    const float* __restrict__ feat, const float* __restrict__ weff,
    const float* __restrict__ beff, float4* __restrict__ tab, int n_nodes) {
    const int lane = threadIdx.x & 63;
    const int wave = (blockIdx.x * blockDim.x + threadIdx.x) >> 6;
    const int v = wave * 2 + (lane >> 5);
    if (wave * 2 >= n_nodes) return;           // wave-uniform exit
    const int vc = v < n_nodes ? v : n_nodes - 1;
    const int t = lane & 31;                   // float4 slot within the row

    const float4 f = ((const float4*)(feat + (long)vc * HIDDEN))[t];
    // top half weights (P): c = t*4..t*4+3, interleaved [c][j] -> 8 floats
    const float4 a0 = *(const float4*)(weff + t * 8);
    const float4 a1 = *(const float4*)(weff + t * 8 + 4);
    // bottom half weights (Q): c+128 -> +256 floats
    const float4 c0 = *(const float4*)(weff + 256 + t * 8);
    const float4 c1 = *(const float4*)(weff + 256 + t * 8 + 4);

    float p0 = f.x*a0.x + f.y*a0.z + f.z*a1.x + f.w*a1.z;
    float p1 = f.x*a0.y + f.y*a0.w + f.z*a1.y + f.w*a1.w;
    float q0 = f.x*c0.x + f.y*c0.z + f.z*c1.x + f.w*c1.z;
    float q1 = f.x*c0.y + f.y*c0.w + f.z*c1.y + f.w*c1.w;

    #pragma unroll
    for (int off = 16; off; off >>= 1) {       // stays within each 32-lane half
        p0 += __shfl_xor(p0, off, 64);
        p1 += __shfl_xor(p1, off, 64);
        q0 += __shfl_xor(q0, off, 64);
        q1 += __shfl_xor(q1, off, 64);
    }

    if (t == 0 && v < n_nodes)
        tab[v] = make_float4(p0 + beff[0], p1 + beff[1], q0, q1);
}

// ---------------------------------------------------------------------------
// Kernel 3: per-edge combine, 2 edges per thread.
//   logit_j = P_j[src] + Q_j[dst]; 2-way softmax.
// int2 index loads (coalesced 8 B), one float4 store covering both edges'
// float2 outputs. The four 8-B table gathers hit the 1.6 MB L2/L3-resident
// tab. Odd tail handled by one extra scalar thread.
// ---------------------------------------------------------------------------
__global__ __launch_bounds__(256) void edge_lite2_kernel(
    const int* __restrict__ edges, const float* __restrict__ tab,
    float* __restrict__ out, int n_edges) {
    const int i = blockIdx.x * blockDim.x + threadIdx.x;   // edge-pair index
    const int npairs = n_edges >> 1;
    if (i < npairs) {
        const int2 s2 = *(const int2*)(edges + 2 * i);
        const int2 d2 = *(const int2*)(edges + n_edges + 2 * i);
        const float2 ps0 = *(const float2*)(tab + (long)s2.x * 4);
        const float2 qd0 = *(const float2*)(tab + (long)d2.x * 4 + 2);
        const float2 ps1 = *(const float2*)(tab + (long)s2.y * 4);
        const float2 qd1 = *(const float2*)(tab + (long)d2.y * 4 + 2);

        const float l00 = ps0.x + qd0.x, l01 = ps0.y + qd0.y;
        const float m0 = fmaxf(l00, l01);
        const float x00 = __expf(l00 - m0), x01 = __expf(l01 - m0);
        const float inv0 = 1.0f / (x00 + x01);

        const float l10 = ps1.x + qd1.x, l11 = ps1.y + qd1.y;
        const float m1 = fmaxf(l10, l11);
        const float x10 = __expf(l10 - m1), x11 = __expf(l11 - m1);
        const float inv1 = 1.0f / (x10 + x11);

        *(float4*)(out + (long)i * 4) =
            make_float4(x00 * inv0, x01 * inv0, x10 * inv1, x11 * inv1);
    } else if (i == npairs && (n_edges & 1)) {
        const int e = n_edges - 1;
        const int s = edges[e];
        const int d = edges[n_edges + e];
        const float2 ps = *(const float2*)(tab + (long)s * 4);
        const float2 qd = *(const float2*)(tab + (long)d * 4 + 2);
        const float l0 = ps.x + qd.x, l1 = ps.y + qd.y;
        const float m = fmaxf(l0, l1);
        const float x0 = __expf(l0 - m), x1 = __expf(l1 - m);
        const float inv = 1.0f / (x0 + x1);
        *(float2*)(out + (long)e * 2) = make_float2(x0 * inv, x1 * inv);
    }
}

// ---------------------------------------------------------------------------
// Fallback (R2-proven fp32 direct edge kernel) — only if ws_size is tiny.
// ---------------------------------------------------------------------------
__global__ __launch_bounds__(256) void edge_kernel(
    const float* __restrict__ feat, const int* __restrict__ edges,
    const float* __restrict__ weff, const float* __restrict__ beff,
    float* __restrict__ out, int n_edges) {
    const int lane = threadIdx.x & 63;
    const int wave = (blockIdx.x * blockDim.x + threadIdx.x) >> 6;
    const int n_waves = (gridDim.x * blockDim.x) >> 6;
    const int g = lane >> 4, sub = lane & 15;
    const int half = sub >> 3, p = sub & 7;

    const float* wb = weff + (half * 128 + p * 16) * 2;
    const float4 w0 = *(const float4*)(wb +  0);
    const float4 w1 = *(const float4*)(wb +  4);
    const float4 w2 = *(const float4*)(wb +  8);
    const float4 w3 = *(const float4*)(wb + 12);
    const float4 w4 = *(const float4*)(wb + 16);
    const float4 w5 = *(const float4*)(wb + 20);
    const float4 w6 = *(const float4*)(wb + 24);
    const float4 w7 = *(const float4*)(wb + 28);
    const float b0 = beff[0], b1v = beff[1];
    const int* idxbase = edges + half * n_edges;

    for (int e0 = wave * 4; e0 < n_edges; e0 += n_waves * 4) {
        const int e  = e0 + g;
        const int ec = e < n_edges ? e : n_edges - 1;
        const int row = idxbase[ec];
        const float* fr = feat + (long)row * HIDDEN + p * 16;
        const float4 f0 = *(const float4*)(fr +  0);
        const float4 f1 = *(const float4*)(fr +  4);
        const float4 f2 = *(const float4*)(fr +  8);
        const float4 f3 = *(const float4*)(fr + 12);
        float a0 = f0.x*w0.x + f0.y*w0.z + f0.z*w1.x + f0.w*w1.z;
        float a1 = f0.x*w0.y + f0.y*w0.w + f0.z*w1.y + f0.w*w1.w;
        a0 += f1.x*w2.x + f1.y*w2.z + f1.z*w3.x + f1.w*w3.z;
        a1 += f1.x*w2.y + f1.y*w2.w + f1.z*w3.y + f1.w*w3.w;
        a0 += f2.x*w4.x + f2.y*w4.z + f2.z*w5.x + f2.w*w5.z;
        a1 += f2.x*w4.y + f2.y*w4.w + f2.z*w5.y + f2.w*w5.w;
        a0 += f3.x*w6.x + f3.y*w6.z + f3.z*w7.x + f3.w*w7.z;
        a1 += f3.x*w6.y + f3.y*w6.w + f3.z*w7.y + f3.w*w7.w;
        #pragma unroll
        for (int off = 8; off; off >>= 1) {
            a0 += __shfl_xor(a0, off, 64);
            a1 += __shfl_xor(a1, off, 64);
        }
        if (sub == 0 && e < n_edges) {
            const float l0 = a0 + b0, l1 = a1 + b1v;
            const float m = fmaxf(l0, l1);
            const float x0 = __expf(l0 - m), x1 = __expf(l1 - m);
            const float inv = 1.0f / (x0 + x1);
            *(float2*)(out + (long)e * 2) = make_float2(x0 * inv, x1 * inv);
        }
    }
}

extern "C" void kernel_launch(void* const* d_in, const int* in_sizes, int n_in,
                              void* d_out, int out_size, void* d_ws, size_t ws_size,
                              hipStream_t stream) {
    const float* feat = (const float*)d_in[0];   // 100000 x 128
    const int*   edges = (const int*)d_in[1];    // 2 x 500000
    const float* W1 = (const float*)d_in[2];     // 256 x 512
    const float* b1 = (const float*)d_in[3];     // 512
    const float* W2 = (const float*)d_in[4];     // 512 x 2
    const float* b2 = (const float*)d_in[5];     // 2
    float* out = (float*)d_out;                  // 500000 x 2

    const int n_nodes = in_sizes[0] / HIDDEN;    // 100000
    const int n_edges = in_sizes[1] / 2;         // 500000

    float* weff = (float*)d_ws;                  // 512 floats @ 0
    float* beff = weff + 512;                    // 2 floats
    float4* tab = (float4*)((char*)d_ws + 4096); // n_nodes x float4
    const size_t need = 4096 + (size_t)n_nodes * sizeof(float4);

    fold_kernel<<<129, 256, 0, stream>>>(W1, b1, W2, b2, weff, beff);

    if (ws_size >= need) {
        // 2 nodes/wave, 4 waves/block
        const int np_blocks = (n_nodes + 7) / 8;
        nodeproj_kernel<<<np_blocks, 256, 0, stream>>>(feat, weff, beff, tab, n_nodes);
        // 2 edges/thread (+1 thread for odd tail)
        const int work = (n_edges >> 1) + (n_edges & 1);
        const int e_blocks = (work + 255) / 256;
        edge_lite2_kernel<<<e_blocks, 256, 0, stream>>>(edges, (const float*)tab,
                                                        out, n_edges);
    } else {
        edge_kernel<<<2048, 256, 0, stream>>>(feat, edges, weff, beff, out, n_edges);
    }
}